// Round 5
// baseline (542.015 us; speedup 1.0000x reference)
//
#include <hip/hip_runtime.h>
#include <cstdint>
#include <cstddef>

typedef _Float16 f16;
typedef _Float16 half8 __attribute__((ext_vector_type(8)));
typedef _Float16 half4 __attribute__((ext_vector_type(4)));
typedef float float4v __attribute__((ext_vector_type(4)));

static __device__ __forceinline__ float4v mfma16(half8 a, half8 b, float4v c) {
  return __builtin_amdgcn_mfma_f32_16x16x32_f16(a, b, c, 0, 0, 0);
}

// ---------------------------------------------------------------------------
// u cell layout: u for logical (b, t, n, g) is stored in the 256-col slice at
// PHYSICAL row R = b*8192 + ((t+1)&127)*64 + (n&~15) + (g>>4), as a 1KB cell
// ordered [lane(q*16+c)][i(4)], q=(n&15)>>2, i=n&3, c=g&15.
//  - GEMM epilogue: one dwordx4 store per acc tile -> 1KB contiguous.
//  - rec load: 1 dwordx4 per wave per step, PURE C++ depth-2 prefetch
//    (LLVM auto-waitcnt brackets the load exactly; correct even w/ spills).
//  - hazard: u(t) lives in slot t+1; h-stores write slot s at step s.
//    load(u(t), issued t-2) completes at the auto-waitcnt before its seed
//    use at step t < barrier(t) < h-write(slot t+1) at step t+1. Sound.
//  - wrap: u(127) lives in slot 0, overwritten at step 0; preloaded into
//    uv127 before the initial __syncthreads and substituted at t==127.
//    (Prefetches at t>=125 read h-overwritten slots: in-bounds, unused.)
// ---------------------------------------------------------------------------

__global__ __launch_bounds__(256, 2) void gemm_u(
    const float* __restrict__ A, int ldA, int K,
    const float* __restrict__ W,
    const float* __restrict__ bias,
    float* __restrict__ outp, int outcol)
{
  __shared__ alignas(16) f16 Ah[4096];
  __shared__ alignas(16) f16 Al[4096];
  __shared__ alignas(16) f16 Bh[8192];
  __shared__ alignas(16) f16 Bl[8192];

  const int tid = threadIdx.x;
  const int w = tid >> 6, lane = tid & 63, q = lane >> 4, c = lane & 15;
  const int mbase = blockIdx.x * 128;
  const int seg = tid & 7, rbase = tid >> 3;

  float4v acc[2][16] = {};
  const int nchunk = K >> 5;

  float4v va[4], vb[8];
  #pragma unroll
  for (int it = 0; it < 4; ++it)
    va[it] = *(const float4v*)(A + (size_t)(mbase + it * 32 + rbase) * ldA + seg * 4);
  #pragma unroll
  for (int it = 0; it < 8; ++it)
    vb[it] = *(const float4v*)(W + (size_t)(it * 32 + rbase) * K + seg * 4);

  for (int kc = 0; kc < nchunk; ++kc) {
    #pragma unroll
    for (int it = 0; it < 4; ++it) {
      int row = it * 32 + rbase;
      float4v v = va[it];
      f16 h0 = (f16)v.x, h1 = (f16)v.y, h2 = (f16)v.z, h3 = (f16)v.w;
      half4 hi = {h0, h1, h2, h3};
      half4 lo = {(f16)(v.x - (float)h0), (f16)(v.y - (float)h1),
                  (f16)(v.z - (float)h2), (f16)(v.w - (float)h3)};
      int mt = row >> 4, m = row & 15, qq = seg >> 1, jj = (seg & 1) * 4;
      int ofs = ((mt * 4 + qq) * 16 + m) * 8 + jj;
      *(half4*)&Ah[ofs] = hi;
      *(half4*)&Al[ofs] = lo;
    }
    #pragma unroll
    for (int it = 0; it < 8; ++it) {
      int g = it * 32 + rbase;
      float4v v = vb[it];
      f16 h0 = (f16)v.x, h1 = (f16)v.y, h2 = (f16)v.z, h3 = (f16)v.w;
      half4 hi = {h0, h1, h2, h3};
      half4 lo = {(f16)(v.x - (float)h0), (f16)(v.y - (float)h1),
                  (f16)(v.z - (float)h2), (f16)(v.w - (float)h3)};
      int nt = g >> 4, n = g & 15, qq = seg >> 1, jj = (seg & 1) * 4;
      int ofs = ((nt * 4 + qq) * 16 + n) * 8 + jj;
      *(half4*)&Bh[ofs] = hi;
      *(half4*)&Bl[ofs] = lo;
    }
    __syncthreads();

    if (kc + 1 < nchunk) {
      int ko = (kc + 1) * 32;
      #pragma unroll
      for (int it = 0; it < 4; ++it)
        va[it] = *(const float4v*)(A + (size_t)(mbase + it * 32 + rbase) * ldA + ko + seg * 4);
      #pragma unroll
      for (int it = 0; it < 8; ++it)
        vb[it] = *(const float4v*)(W + (size_t)(it * 32 + rbase) * K + ko + seg * 4);
    }

    half8 ah[2], al[2];
    #pragma unroll
    for (int m2 = 0; m2 < 2; ++m2) {
      int mt = w * 2 + m2;
      int ofs = ((mt * 4 + q) * 16 + c) * 8;
      ah[m2] = *(half8*)&Ah[ofs];
      al[m2] = *(half8*)&Al[ofs];
    }
    #pragma unroll
    for (int nt = 0; nt < 16; ++nt) {
      int ofs = ((nt * 4 + q) * 16 + c) * 8;
      half8 bh = *(half8*)&Bh[ofs];
      half8 bl = *(half8*)&Bl[ofs];
      #pragma unroll
      for (int m2 = 0; m2 < 2; ++m2) {
        acc[m2][nt] = mfma16(ah[m2], bh, acc[m2][nt]);
        acc[m2][nt] = mfma16(al[m2], bh, acc[m2][nt]);
        acc[m2][nt] = mfma16(ah[m2], bl, acc[m2][nt]);
      }
    }
    __syncthreads();
  }

  #pragma unroll
  for (int m2 = 0; m2 < 2; ++m2) {
    const int m2t = w * 2 + m2;
    const int b_ = mbase >> 13;
    const int t_ = ((mbase >> 6) + (m2t >> 2)) & 127;
    const int n0 = (m2t & 3) * 16;
    const size_t rowbase =
        ((size_t)b_ * 8192 + (size_t)((t_ + 1) & 127) * 64 + n0) * 768
        + outcol + (q * 16 + c) * 4;
    #pragma unroll
    for (int nt = 0; nt < 16; ++nt) {
      const float bsv = bias[nt * 16 + c];
      float4v vst;
      vst.x = acc[m2][nt][0] + bsv;
      vst.y = acc[m2][nt][1] + bsv;
      vst.z = acc[m2][nt][2] + bsv;
      vst.w = acc[m2][nt][3] + bsv;
      *(float4v*)&outp[rowbase + (size_t)nt * 768] = vst;
    }
  }
}

// ---------------------------------------------------------------------------
// rec_layer v8: v5 structure (32 blocks x 16 waves, W_hh B-frags in regs,
// h double-buffered in LDS A-frag order, u seeded into the MFMA accumulator,
// cheap tanh) + DEPTH-2 u prefetch in pure C++ (uvc/uvn1/uvn2 rotation).
// No inline-asm VMEM, no hand-counted vmcnt: LLVM's waitcnt pass emits the
// minimal bracket (the per-step barrier asm's "memory" clobber keeps each
// load inside its own iteration, so the load issued at step t is consumed
// at t+2 with ~2 full steps of latency cover).
// per-step sync = raw "s_waitcnt lgkmcnt(0); s_barrier" (LDS order only;
// h-stores and prefetches stay in flight).
// ---------------------------------------------------------------------------
__global__ __launch_bounds__(1024, 1) void rec_layer(
    float* __restrict__ io, const float* __restrict__ whh, int outcol)
{
  __shared__ alignas(16) f16 hbuf[2][4096];  // [buf][kc(8)][quad(4)][m(16)][j(8)]

  const int tid = threadIdx.x;
  const int w = tid >> 6, lane = tid & 63, q = lane >> 4, c = lane & 15;
  const int r0 = blockIdx.x * 16;
  const int b_ = r0 >> 6, n0 = r0 & 63;
  const int gcol = w * 16 + c;

  // W_hh B-fragments: wf[kc] -> B[k=kc*32+q*8+j][n=gcol]
  half8 wf[8];
  #pragma unroll
  for (int kc = 0; kc < 8; ++kc) {
    const float* src = whh + (size_t)gcol * 256 + kc * 32 + q * 8;
    float4v v0 = *(const float4v*)src;
    float4v v1 = *(const float4v*)(src + 4);
    wf[kc] = (half8){(f16)v0.x, (f16)v0.y, (f16)v0.z, (f16)v0.w,
                     (f16)v1.x, (f16)v1.y, (f16)v1.z, (f16)v1.w};
  }

  // zero both h buffers (h0 = 0); 16384 B = 4096 dwords, 1024 threads
  {
    uint32_t* p = (uint32_t*)hbuf;
    #pragma unroll
    for (int i = 0; i < 4; ++i) p[tid + i * 1024] = 0u;
  }

  float hreg[4] = {};
  size_t base[4];
  #pragma unroll
  for (int i = 0; i < 4; ++i) {
    const int r = r0 + q * 4 + i;
    base[i] = ((size_t)(r >> 6) * 8192 + (r & 63)) * 768 + outcol + gcol;
  }

  // u cell base for this (block, wave, lane): row b*8192 + 0 + n0 + w
  const size_t ucell0 =
      ((size_t)b_ * 8192 + n0 + w) * 768 + outcol + (q * 16 + c) * 4;

  // preload u(127)@slot0 -> uv127, u(0)@slot1 -> uvc, u(1)@slot2 -> uvn1
  float4v uv127 = *(const float4v*)&io[ucell0];
  float4v uvc   = *(const float4v*)&io[ucell0 + 49152];
  float4v uvn1  = *(const float4v*)&io[ucell0 + 2 * 49152];

  const int widx = (((gcol >> 5) * 4 + ((gcol >> 3) & 3)) * 16) * 8 + (gcol & 7);

  __syncthreads();   // full drain; preloads + zero-fill complete

  for (int t = 0; t < 128; ++t) {
    const f16* rb = hbuf[t & 1];
    f16* wb = hbuf[(t + 1) & 1];

    // A-fragments of h_{t-1} (conflict-free ds_read_b128)
    half8 af[8];
    #pragma unroll
    for (int kc = 0; kc < 8; ++kc)
      af[kc] = *(const half8*)&rb[((kc * 4 + q) * 16 + c) * 8];

    // depth-2 prefetch: u(t+2) lives at slot (t+3)&127. (t>=125 reads
    // h-overwritten slots: in-bounds, value unused / substituted below.)
    float4v uvn2 = *(const float4v*)&io[ucell0 + (size_t)((t + 3) & 127) * 49152];

    // seed: u(t); at t==127 the slot was overwritten at step 0 -> uv127
    float4v useed = uvc;
    if (t == 127) useed = uv127;

    // rec = u_t + h_{t-1} @ W_hh^T : 8 MFMAs, 2 chains of depth 4
    float4v acc0 = useed;
    float4v acc1 = (float4v){0.f, 0.f, 0.f, 0.f};
    #pragma unroll
    for (int kc = 0; kc < 4; ++kc) {
      acc0 = mfma16(af[kc], wf[kc], acc0);
      acc1 = mfma16(af[kc + 4], wf[kc + 4], acc1);
    }

    // tanh + blend; h -> global (fire-and-forget) + LDS A-layout for t+1
    const size_t sofs = (size_t)t * 49152;
    #pragma unroll
    for (int i = 0; i < 4; ++i) {
      const float xv = acc0[i] + acc1[i];
      // tanh(x) = 1 - 2/(exp2(2*log2e*x)+1); rcp/exp2 are HW-approx (~1ulp)
      const float e  = __builtin_amdgcn_exp2f(xv * 2.8853900817779268f);
      const float rr = __builtin_amdgcn_rcpf(e + 1.0f);
      const float hn = fmaf(-1.8f, rr, fmaf(0.1f, hreg[i], 0.9f));
      hreg[i] = hn;
      io[base[i] + sofs] = hn;
      wb[widx + (q * 4 + i) * 8] = (f16)hn;
    }

    if (t != 127) {
      // order LDS only; vmcnt stays un-drained (prefetch + stores fly)
      asm volatile("s_waitcnt lgkmcnt(0)\n\ts_barrier" ::: "memory");
    }

    // rotate the prefetch pipeline (register renames, SSA'd away)
    uvc  = uvn1;
    uvn1 = uvn2;
  }
}

extern "C" void kernel_launch(void* const* d_in, const int* in_sizes, int n_in,
                              void* d_out, int out_size, void* d_ws, size_t ws_size,
                              hipStream_t stream) {
  (void)in_sizes; (void)n_in; (void)out_size; (void)d_ws; (void)ws_size;
  const float* x     = (const float*)d_in[0];   // [8,128,64,32]
  const float* w_ih0 = (const float*)d_in[1];   // [256,32]
  const float* w_ih  = (const float*)d_in[2];   // [2,256,256]
  const float* b_ih  = (const float*)d_in[3];   // [3,256]
  const float* w_hh  = (const float*)d_in[4];   // [3,256,256]
  float* out = (float*)d_out;                   // [8,128,64,768] fp32

  gemm_u<<<512, 256, 0, stream>>>(x,         32,  32, w_ih0,         b_ih,       out, 0);
  rec_layer<<<32, 1024, 0, stream>>>(out, w_hh,            0);
  gemm_u<<<512, 256, 0, stream>>>(out,       768, 256, w_ih,          b_ih + 256, out, 256);
  rec_layer<<<32, 1024, 0, stream>>>(out, w_hh + 65536,    256);
  gemm_u<<<512, 256, 0, stream>>>(out + 256, 768, 256, w_ih + 65536,  b_ih + 512, out, 512);
  rec_layer<<<32, 1024, 0, stream>>>(out, w_hh + 131072,   512);
}

// Round 7
// 529.062 us; speedup vs baseline: 1.0245x; 1.0245x over previous
//
#include <hip/hip_runtime.h>
#include <cstdint>
#include <cstddef>

typedef _Float16 f16;
typedef _Float16 half8 __attribute__((ext_vector_type(8)));
typedef _Float16 half4 __attribute__((ext_vector_type(4)));
typedef float float4v __attribute__((ext_vector_type(4)));

static __device__ __forceinline__ float4v mfma16(half8 a, half8 b, float4v c) {
  return __builtin_amdgcn_mfma_f32_16x16x32_f16(a, b, c, 0, 0, 0);
}

static __device__ __forceinline__ void gload_lds16(const void* g, void* l) {
  __builtin_amdgcn_global_load_lds(
      (const __attribute__((address_space(1))) void*)g,
      (__attribute__((address_space(3))) void*)l, 16, 0, 0);
}

// ---------------------------------------------------------------------------
// u cell layout: u for logical (b, t, n, g) is stored in the 256-col slice at
// PHYSICAL row R = b*8192 + ((t+1)&127)*64 + (n&~15) + (g>>4), as a 1KB cell
// ordered [lane(q*16+c)][i(4)], q=(n&15)>>2, i=n&3, c=g&15.
//  - GEMM epilogue: one dwordx4 store per acc tile -> 1KB contiguous.
//  - rec load: 1 dwordx4 per wave per step.
//  - hazard: cell(s) lives in rows h-overwritten at step s+1 BY THE SAME
//    BLOCK; consume-wait(start of s) < barrier(s) < h-write(s+1). Sound.
//  - wrap: cell(127) lives in rows(0); preloaded before the initial
//    __syncthreads (full drain) -> precedes any h-write.
// ---------------------------------------------------------------------------

// prep_w: convert W_ih[l] (256x256 f32) into MFMA-fragment-ordered hi/lo f16
// planes in workspace:  ws + l*131072 = [hi 65536 f16][lo 65536 f16],
// frag[kc*8192 + ((nt*4+qq)*16+n)*8 + j] = W[g=nt*16+n][k=kc*32+qq*8+j].
// Bit-identical values to the old in-kernel staging (same cvt ops).
__global__ __launch_bounds__(256) void prep_w(
    const float* __restrict__ w_ih, f16* __restrict__ wsf)
{
  const int idx = blockIdx.x * 256 + threadIdx.x;   // 0..131071
  const int l = idx >> 16, e = idx & 65535;
  const int g = e >> 8, k = e & 255;
  const float v = w_ih[(size_t)l * 65536 + e];
  const f16 hi = (f16)v;
  const f16 lo = (f16)(v - (float)hi);
  const int kc = k >> 5, qq = (k >> 3) & 3, j = k & 7;
  const int nt = g >> 4, n = g & 15;
  const int fofs = kc * 8192 + ((nt * 4 + qq) * 16 + n) * 8 + j;
  wsf[(size_t)l * 131072 + fofs] = hi;
  wsf[(size_t)l * 131072 + 65536 + fofs] = lo;
}

// ---------------------------------------------------------------------------
// gemm_u (generic-K, in-kernel B staging) — used for layer 0 (K=32) and as
// the fallback when the workspace is too small for prep_w.
// ---------------------------------------------------------------------------
__global__ __launch_bounds__(256, 2) void gemm_u(
    const float* __restrict__ A, int ldA, int K,
    const float* __restrict__ W,
    const float* __restrict__ bias,
    float* __restrict__ outp, int outcol)
{
  __shared__ alignas(16) f16 Ah[4096];
  __shared__ alignas(16) f16 Al[4096];
  __shared__ alignas(16) f16 Bh[8192];
  __shared__ alignas(16) f16 Bl[8192];

  const int tid = threadIdx.x;
  const int w = tid >> 6, lane = tid & 63, q = lane >> 4, c = lane & 15;
  const int mbase = blockIdx.x * 128;
  const int seg = tid & 7, rbase = tid >> 3;

  float4v acc[2][16] = {};
  const int nchunk = K >> 5;

  float4v va[4], vb[8];
  #pragma unroll
  for (int it = 0; it < 4; ++it)
    va[it] = *(const float4v*)(A + (size_t)(mbase + it * 32 + rbase) * ldA + seg * 4);
  #pragma unroll
  for (int it = 0; it < 8; ++it)
    vb[it] = *(const float4v*)(W + (size_t)(it * 32 + rbase) * K + seg * 4);

  for (int kc = 0; kc < nchunk; ++kc) {
    #pragma unroll
    for (int it = 0; it < 4; ++it) {
      int row = it * 32 + rbase;
      float4v v = va[it];
      f16 h0 = (f16)v.x, h1 = (f16)v.y, h2 = (f16)v.z, h3 = (f16)v.w;
      half4 hi = {h0, h1, h2, h3};
      half4 lo = {(f16)(v.x - (float)h0), (f16)(v.y - (float)h1),
                  (f16)(v.z - (float)h2), (f16)(v.w - (float)h3)};
      int mt = row >> 4, m = row & 15, qq = seg >> 1, jj = (seg & 1) * 4;
      int ofs = ((mt * 4 + qq) * 16 + m) * 8 + jj;
      *(half4*)&Ah[ofs] = hi;
      *(half4*)&Al[ofs] = lo;
    }
    #pragma unroll
    for (int it = 0; it < 8; ++it) {
      int g = it * 32 + rbase;
      float4v v = vb[it];
      f16 h0 = (f16)v.x, h1 = (f16)v.y, h2 = (f16)v.z, h3 = (f16)v.w;
      half4 hi = {h0, h1, h2, h3};
      half4 lo = {(f16)(v.x - (float)h0), (f16)(v.y - (float)h1),
                  (f16)(v.z - (float)h2), (f16)(v.w - (float)h3)};
      int nt = g >> 4, n = g & 15, qq = seg >> 1, jj = (seg & 1) * 4;
      int ofs = ((nt * 4 + qq) * 16 + n) * 8 + jj;
      *(half4*)&Bh[ofs] = hi;
      *(half4*)&Bl[ofs] = lo;
    }
    __syncthreads();

    if (kc + 1 < nchunk) {
      int ko = (kc + 1) * 32;
      #pragma unroll
      for (int it = 0; it < 4; ++it)
        va[it] = *(const float4v*)(A + (size_t)(mbase + it * 32 + rbase) * ldA + ko + seg * 4);
      #pragma unroll
      for (int it = 0; it < 8; ++it)
        vb[it] = *(const float4v*)(W + (size_t)(it * 32 + rbase) * K + ko + seg * 4);
    }

    half8 ah[2], al[2];
    #pragma unroll
    for (int m2 = 0; m2 < 2; ++m2) {
      int mt = w * 2 + m2;
      int ofs = ((mt * 4 + q) * 16 + c) * 8;
      ah[m2] = *(half8*)&Ah[ofs];
      al[m2] = *(half8*)&Al[ofs];
    }
    #pragma unroll
    for (int nt = 0; nt < 16; ++nt) {
      int ofs = ((nt * 4 + q) * 16 + c) * 8;
      half8 bh = *(half8*)&Bh[ofs];
      half8 bl = *(half8*)&Bl[ofs];
      #pragma unroll
      for (int m2 = 0; m2 < 2; ++m2) {
        acc[m2][nt] = mfma16(ah[m2], bh, acc[m2][nt]);
        acc[m2][nt] = mfma16(al[m2], bh, acc[m2][nt]);
        acc[m2][nt] = mfma16(ah[m2], bl, acc[m2][nt]);
      }
    }
    __syncthreads();
  }

  #pragma unroll
  for (int m2 = 0; m2 < 2; ++m2) {
    const int m2t = w * 2 + m2;
    const int b_ = mbase >> 13;
    const int t_ = ((mbase >> 6) + (m2t >> 2)) & 127;
    const int n0 = (m2t & 3) * 16;
    const size_t rowbase =
        ((size_t)b_ * 8192 + (size_t)((t_ + 1) & 127) * 64 + n0) * 768
        + outcol + (q * 16 + c) * 4;
    #pragma unroll
    for (int nt = 0; nt < 16; ++nt) {
      const float bsv = bias[nt * 16 + c];
      float4v vst;
      vst.x = acc[m2][nt][0] + bsv;
      vst.y = acc[m2][nt][1] + bsv;
      vst.z = acc[m2][nt][2] + bsv;
      vst.w = acc[m2][nt][3] + bsv;
      *(float4v*)&outp[rowbase + (size_t)nt * 768] = vst;
    }
  }
}

// ---------------------------------------------------------------------------
// gemm_u_pw (K=256, prepped-W): B staged via global_load_lds 16B DMA from
// the fragment-ordered hi/lo planes in workspace — zero B cvt VALU, zero B
// LDS-write instructions, B bytes halved, DMA overlaps the A-staging VALU.
// A path / MFMA order identical to gemm_u -> bit-identical results.
// ---------------------------------------------------------------------------
__global__ __launch_bounds__(256, 2) void gemm_u_pw(
    const float* __restrict__ A, int ldA,
    const f16* __restrict__ Wf,     // [hi 65536][lo 65536] fragment-ordered
    const float* __restrict__ bias,
    float* __restrict__ outp, int outcol)
{
  __shared__ alignas(16) f16 Ah[4096];
  __shared__ alignas(16) f16 Al[4096];
  __shared__ alignas(16) f16 Bh[8192];
  __shared__ alignas(16) f16 Bl[8192];

  const int tid = threadIdx.x;
  const int w = tid >> 6, lane = tid & 63, q = lane >> 4, c = lane & 15;
  const int mbase = blockIdx.x * 128;
  const int seg = tid & 7, rbase = tid >> 3;

  float4v acc[2][16] = {};

  float4v va[4];
  #pragma unroll
  for (int it = 0; it < 4; ++it)
    va[it] = *(const float4v*)(A + (size_t)(mbase + it * 32 + rbase) * ldA + seg * 4);

  for (int kc = 0; kc < 8; ++kc) {
    // ---- B staging: 8 DMA issues per wave (4 hi + 4 lo), 1KB each.
    // frag source is linear in exactly the LDS order; lane i lands at
    // ldsbase + i*16 (wave-uniform base, m97 pattern).
    #pragma unroll
    for (int r = 0; r < 4; ++r) {
      const int fo = kc * 8192 + (w * 4 + r) * 512;     // f16 units
      gload_lds16(Wf + fo + lane * 8,          &Bh[(w * 4 + r) * 512]);
      gload_lds16(Wf + 65536 + fo + lane * 8,  &Bl[(w * 4 + r) * 512]);
    }

    // ---- A staging (unchanged math): cvt hi/lo, permuted LDS writes.
    #pragma unroll
    for (int it = 0; it < 4; ++it) {
      int row = it * 32 + rbase;
      float4v v = va[it];
      f16 h0 = (f16)v.x, h1 = (f16)v.y, h2 = (f16)v.z, h3 = (f16)v.w;
      half4 hi = {h0, h1, h2, h3};
      half4 lo = {(f16)(v.x - (float)h0), (f16)(v.y - (float)h1),
                  (f16)(v.z - (float)h2), (f16)(v.w - (float)h3)};
      int mt = row >> 4, m = row & 15, qq = seg >> 1, jj = (seg & 1) * 4;
      int ofs = ((mt * 4 + qq) * 16 + m) * 8 + jj;
      *(half4*)&Ah[ofs] = hi;
      *(half4*)&Al[ofs] = lo;
    }
    __syncthreads();   // compiler drains vmcnt (DMA) + lgkmcnt before barrier

    if (kc + 1 < 8) {
      int ko = (kc + 1) * 32;
      #pragma unroll
      for (int it = 0; it < 4; ++it)
        va[it] = *(const float4v*)(A + (size_t)(mbase + it * 32 + rbase) * ldA + ko + seg * 4);
    }

    half8 ah[2], al[2];
    #pragma unroll
    for (int m2 = 0; m2 < 2; ++m2) {
      int mt = w * 2 + m2;
      int ofs = ((mt * 4 + q) * 16 + c) * 8;
      ah[m2] = *(half8*)&Ah[ofs];
      al[m2] = *(half8*)&Al[ofs];
    }
    #pragma unroll
    for (int nt = 0; nt < 16; ++nt) {
      int ofs = ((nt * 4 + q) * 16 + c) * 8;
      half8 bh = *(half8*)&Bh[ofs];
      half8 bl = *(half8*)&Bl[ofs];
      #pragma unroll
      for (int m2 = 0; m2 < 2; ++m2) {
        acc[m2][nt] = mfma16(ah[m2], bh, acc[m2][nt]);
        acc[m2][nt] = mfma16(al[m2], bh, acc[m2][nt]);
        acc[m2][nt] = mfma16(ah[m2], bl, acc[m2][nt]);
      }
    }
    __syncthreads();
  }

  #pragma unroll
  for (int m2 = 0; m2 < 2; ++m2) {
    const int m2t = w * 2 + m2;
    const int b_ = mbase >> 13;
    const int t_ = ((mbase >> 6) + (m2t >> 2)) & 127;
    const int n0 = (m2t & 3) * 16;
    const size_t rowbase =
        ((size_t)b_ * 8192 + (size_t)((t_ + 1) & 127) * 64 + n0) * 768
        + outcol + (q * 16 + c) * 4;
    #pragma unroll
    for (int nt = 0; nt < 16; ++nt) {
      const float bsv = bias[nt * 16 + c];
      float4v vst;
      vst.x = acc[m2][nt][0] + bsv;
      vst.y = acc[m2][nt][1] + bsv;
      vst.z = acc[m2][nt][2] + bsv;
      vst.w = acc[m2][nt][3] + bsv;
      *(float4v*)&outp[rowbase + (size_t)nt * 768] = vst;
    }
  }
}

// ---------------------------------------------------------------------------
// rec_layer v5 (R2-measured best): 32 blocks x 16 waves, W_hh B-frags in
// regs, h double-buffered in LDS A-frag order, u folded into the MFMA
// accumulator init, cheap tanh via v_exp_f32 + v_rcp_f32.
// per-step sync = raw "s_waitcnt lgkmcnt(0); s_barrier".
// ---------------------------------------------------------------------------
__global__ __launch_bounds__(1024, 1) void rec_layer(
    float* __restrict__ io, const float* __restrict__ whh, int outcol)
{
  __shared__ alignas(16) f16 hbuf[2][4096];  // [buf][kc(8)][quad(4)][m(16)][j(8)]

  const int tid = threadIdx.x;
  const int w = tid >> 6, lane = tid & 63, q = lane >> 4, c = lane & 15;
  const int r0 = blockIdx.x * 16;
  const int b_ = r0 >> 6, n0 = r0 & 63;
  const int gcol = w * 16 + c;

  // W_hh B-fragments: wf[kc] -> B[k=kc*32+q*8+j][n=gcol]
  half8 wf[8];
  #pragma unroll
  for (int kc = 0; kc < 8; ++kc) {
    const float* src = whh + (size_t)gcol * 256 + kc * 32 + q * 8;
    float4v v0 = *(const float4v*)src;
    float4v v1 = *(const float4v*)(src + 4);
    wf[kc] = (half8){(f16)v0.x, (f16)v0.y, (f16)v0.z, (f16)v0.w,
                     (f16)v1.x, (f16)v1.y, (f16)v1.z, (f16)v1.w};
  }

  // zero both h buffers (h0 = 0); 16384 B = 4096 dwords, 1024 threads
  {
    uint32_t* p = (uint32_t*)hbuf;
    #pragma unroll
    for (int i = 0; i < 4; ++i) p[tid + i * 1024] = 0u;
  }

  float hreg[4] = {};
  size_t base[4];
  #pragma unroll
  for (int i = 0; i < 4; ++i) {
    const int r = r0 + q * 4 + i;
    base[i] = ((size_t)(r >> 6) * 8192 + (r & 63)) * 768 + outcol + gcol;
  }

  // u cell base for this (block, wave, lane): row b*8192 + 0 + n0 + w
  const size_t ucell0 =
      ((size_t)b_ * 8192 + n0 + w) * 768 + outcol + (q * 16 + c) * 4;

  // preload cell(127)@slot0, u(0)@slot1
  float4v uv127, uvc;
  uv127 = *(const float4v*)&io[ucell0];
  uvc   = *(const float4v*)&io[ucell0 + 49152];

  const int widx = (((gcol >> 5) * 4 + ((gcol >> 3) & 3)) * 16) * 8 + (gcol & 7);

  __syncthreads();   // full drain; preloads + zero-fill complete

  for (int t = 0; t < 128; ++t) {
    const f16* rb = hbuf[t & 1];
    f16* wb = hbuf[(t + 1) & 1];

    // A-fragments of h_{t-1} (conflict-free ds_read_b128)
    half8 af[8];
    #pragma unroll
    for (int kc = 0; kc < 8; ++kc)
      af[kc] = *(const half8*)&rb[((kc * 4 + q) * 16 + c) * 8];

    // prefetch u for step t+1 (cell @ rows(t+2)); t=126 -> have uv127
    float4v uvn;
    if (t < 126)
      uvn = *(const float4v*)&io[ucell0 + (size_t)(t + 2) * 49152];

    // rec = u_t + h_{t-1} @ W_hh^T : 8 MFMAs, 2 chains of depth 4
    float4v acc0 = uvc;
    float4v acc1 = (float4v){0.f, 0.f, 0.f, 0.f};
    #pragma unroll
    for (int kc = 0; kc < 4; ++kc) {
      acc0 = mfma16(af[kc], wf[kc], acc0);
      acc1 = mfma16(af[kc + 4], wf[kc + 4], acc1);
    }

    // tanh + blend; h -> global (fire-and-forget) + LDS A-layout for t+1
    const size_t sofs = (size_t)t * 49152;
    #pragma unroll
    for (int i = 0; i < 4; ++i) {
      const float xv = acc0[i] + acc1[i];
      // tanh(x) = 1 - 2/(exp2(2*log2e*x)+1); rcp/exp2 are HW-approx (~1ulp)
      const float e  = __builtin_amdgcn_exp2f(xv * 2.8853900817779268f);
      const float rr = __builtin_amdgcn_rcpf(e + 1.0f);
      const float hn = fmaf(-1.8f, rr, fmaf(0.1f, hreg[i], 0.9f));
      hreg[i] = hn;
      io[base[i] + sofs] = hn;
      wb[widx + (q * 4 + i) * 8] = (f16)hn;
    }

    if (t < 127) {
      // order LDS only; do NOT drain vmcnt (stores/prefetch stay in flight)
      asm volatile("s_waitcnt lgkmcnt(0)\n\ts_barrier" ::: "memory");
      uvc = (t == 126) ? uv127 : uvn;
    }
  }
}

extern "C" void kernel_launch(void* const* d_in, const int* in_sizes, int n_in,
                              void* d_out, int out_size, void* d_ws, size_t ws_size,
                              hipStream_t stream) {
  (void)in_sizes; (void)n_in; (void)out_size;
  const float* x     = (const float*)d_in[0];   // [8,128,64,32]
  const float* w_ih0 = (const float*)d_in[1];   // [256,32]
  const float* w_ih  = (const float*)d_in[2];   // [2,256,256]
  const float* b_ih  = (const float*)d_in[3];   // [3,256]
  const float* w_hh  = (const float*)d_in[4];   // [3,256,256]
  float* out = (float*)d_out;                   // [8,128,64,768] fp32

  if (ws_size >= 2u * 131072u * sizeof(f16)) {
    f16* wsf = (f16*)d_ws;                      // [2 layers][hi|lo][65536]
    prep_w<<<512, 256, 0, stream>>>(w_ih, wsf);
    gemm_u<<<512, 256, 0, stream>>>(x, 32, 32, w_ih0, b_ih, out, 0);
    rec_layer<<<32, 1024, 0, stream>>>(out, w_hh, 0);
    gemm_u_pw<<<512, 256, 0, stream>>>(out, 768, wsf, b_ih + 256, out, 256);
    rec_layer<<<32, 1024, 0, stream>>>(out, w_hh + 65536, 256);
    gemm_u_pw<<<512, 256, 0, stream>>>(out + 256, 768, wsf + 131072, b_ih + 512, out, 512);
    rec_layer<<<32, 1024, 0, stream>>>(out, w_hh + 131072, 512);
  } else {
    gemm_u<<<512, 256, 0, stream>>>(x, 32, 32, w_ih0, b_ih, out, 0);
    rec_layer<<<32, 1024, 0, stream>>>(out, w_hh, 0);
    gemm_u<<<512, 256, 0, stream>>>(out, 768, 256, w_ih, b_ih + 256, out, 256);
    rec_layer<<<32, 1024, 0, stream>>>(out, w_hh + 65536, 256);
    gemm_u<<<512, 256, 0, stream>>>(out + 256, 768, 256, w_ih + 65536, b_ih + 512, out, 512);
    rec_layer<<<32, 1024, 0, stream>>>(out, w_hh + 131072, 512);
  }
}